// Round 6
// baseline (104.720 us; speedup 1.0000x reference)
//
#include <hip/hip_runtime.h>
#include <hip/hip_bf16.h>

// Reference collapses to: out[i, :] = tokens[i, :] * (probs[i,0] + probs[i,1]).
// The gather/argsort/scatter_add round-trip is the identity permutation.
// Indices input is unused. Pure memory-bound streaming scale.
//
// R3: nontemporal regressed (-20 us). R4: block-contiguous + 4-deep = 105.1.
// R5: 8-deep + scalar probs = 104.4 (noise). R6: full unroll of the outer
// loop so the compiler software-pipelines loads across store phases
// (continuous read stream), + all 8 row-scales hoisted to block entry.

#define N_TOKENS 16384
#define HIDDEN   4096

#define BLOCK    256
#define TOTAL4   (N_TOKENS * (HIDDEN / 4))    // 16777216 float4
#define GRID     2048
#define PER_BLK  (TOTAL4 / GRID)              // 8192 float4 = 8 rows = 128 KiB
#define ROWS_PER_BLK (PER_BLK / (HIDDEN / 4)) // 8
#define NBATCH   8                            // loads in flight per batch
#define NITER    (PER_BLK / (BLOCK * NBATCH)) // 4

typedef float f32x4 __attribute__((ext_vector_type(4)));
typedef float f32x2 __attribute__((ext_vector_type(2)));

__global__ __launch_bounds__(BLOCK) void moe_scale_kernel(
    const f32x4* __restrict__ tokens4,
    const f32x2* __restrict__ probs2,
    f32x4* __restrict__ out4)
{
    const int bid  = blockIdx.x;
    const int base = bid * PER_BLK + threadIdx.x;   // fits in 32-bit

    // All 8 row-scales up front: uniform address -> scalar loads
    // (8 contiguous f32x2 = 64B, mergeable into s_load_dwordx16).
    float s[ROWS_PER_BLK];
#pragma unroll
    for (int r = 0; r < ROWS_PER_BLK; ++r) {
        const f32x2 p = probs2[bid * ROWS_PER_BLK + r];
        s[r] = p.x + p.y;
    }

    // Fully unrolled: compiler sees all 32 loads + 32 stores and can keep
    // the read stream continuously busy across store phases.
#pragma unroll
    for (int it = 0; it < NITER; ++it) {
        f32x4 v[NBATCH];
#pragma unroll
        for (int u = 0; u < NBATCH; ++u)
            v[u] = tokens4[base + (it * NBATCH + u) * BLOCK];
#pragma unroll
        for (int u = 0; u < NBATCH; ++u) {
            // chunk (it*NBATCH+u) spans 256 float4 = quarter-row; row = chunk/4
            const int row = (it * NBATCH + u) >> 2;
            out4[base + (it * NBATCH + u) * BLOCK] = v[u] * s[row];
        }
    }
}

extern "C" void kernel_launch(void* const* d_in, const int* in_sizes, int n_in,
                              void* d_out, int out_size, void* d_ws, size_t ws_size,
                              hipStream_t stream) {
    const f32x4* tokens4 = (const f32x4*)d_in[0];
    const f32x2* probs2  = (const f32x2*)d_in[1];
    // d_in[2] (indices) intentionally unused — see derivation above.
    f32x4* out4 = (f32x4*)d_out;

    moe_scale_kernel<<<GRID, BLOCK, 0, stream>>>(tokens4, probs2, out4);
}

// Round 7
// 85.403 us; speedup vs baseline: 1.2262x; 1.2262x over previous
//
#include <hip/hip_runtime.h>
#include <hip/hip_bf16.h>

// Reference collapses to: out[i, :] = tokens[i, :] * (probs[i,0] + probs[i,1]).
// The gather/argsort/scatter_add round-trip is the identity permutation.
// Indices input is unused. Pure memory-bound streaming scale.
//
// R3: nt on BOTH loads+stores regressed (-20 us). R4: block-contiguous +
// 4-deep = 105.1. R5: 8-deep + scalar probs = 104.4. R6: full unroll = 104.7
// (flat x3 at 5.14 TB/s). R7: test the untested cell — CACHED loads +
// NON-TEMPORAL stores only. Writes stop write-allocating in L2/L3, read
// stream gets the whole 256 MiB L3 (input is exactly L3-sized).

#define N_TOKENS 16384
#define HIDDEN   4096

#define BLOCK    256
#define TOTAL4   (N_TOKENS * (HIDDEN / 4))    // 16777216 float4
#define GRID     2048
#define PER_BLK  (TOTAL4 / GRID)              // 8192 float4 = 8 rows = 128 KiB
#define ROWS_PER_BLK (PER_BLK / (HIDDEN / 4)) // 8
#define NBATCH   8                            // loads in flight per batch
#define NITER    (PER_BLK / (BLOCK * NBATCH)) // 4

typedef float f32x4 __attribute__((ext_vector_type(4)));
typedef float f32x2 __attribute__((ext_vector_type(2)));

__global__ __launch_bounds__(BLOCK) void moe_scale_kernel(
    const f32x4* __restrict__ tokens4,
    const f32x2* __restrict__ probs2,
    f32x4* __restrict__ out4)
{
    const int bid  = blockIdx.x;
    const int base = bid * PER_BLK + threadIdx.x;   // fits in 32-bit

    // All 8 row-scales up front: uniform address -> scalar loads.
    float s[ROWS_PER_BLK];
#pragma unroll
    for (int r = 0; r < ROWS_PER_BLK; ++r) {
        const f32x2 p = probs2[bid * ROWS_PER_BLK + r];
        s[r] = p.x + p.y;
    }

#pragma unroll
    for (int it = 0; it < NITER; ++it) {
        f32x4 v[NBATCH];
#pragma unroll
        for (int u = 0; u < NBATCH; ++u)
            v[u] = tokens4[base + (it * NBATCH + u) * BLOCK];   // cached reads
#pragma unroll
        for (int u = 0; u < NBATCH; ++u) {
            const int row = (it * NBATCH + u) >> 2;
            f32x4 r = v[u] * s[row];
            __builtin_nontemporal_store(r, &out4[base + (it * NBATCH + u) * BLOCK]);
        }
    }
}

extern "C" void kernel_launch(void* const* d_in, const int* in_sizes, int n_in,
                              void* d_out, int out_size, void* d_ws, size_t ws_size,
                              hipStream_t stream) {
    const f32x4* tokens4 = (const f32x4*)d_in[0];
    const f32x2* probs2  = (const f32x2*)d_in[1];
    // d_in[2] (indices) intentionally unused — see derivation above.
    f32x4* out4 = (f32x4*)d_out;

    moe_scale_kernel<<<GRID, BLOCK, 0, stream>>>(tokens4, probs2, out4);
}